// Round 8
// baseline (1129.709 us; speedup 1.0000x reference)
//
#include <hip/hip_runtime.h>

// 2-layer LSTM, B=512, T=1024, H=64 (tf LSTMCell, gates i,j,f,o, forget bias 1.0)
//
// ROUND-8: 3 waves per batch element (192 thr), grid 512 (2 blocks/CU).
//   Waves 0-1 (compute): wave w owns gates {2w, 2w+1} = 130 W1 weights in
//   VGPRs (resident via amdgpu_waves_per_eu(1,1) + one-shot opaque asm pins —
//   proven rounds 6-7: VGPR=132, no remat, no spill). Per step: 64 readlane
//   broadcasts of register-resident hv feed 128 FMAs; acts -> gls (gate-major,
//   conflict-free); ONE barrier; cell update (replicated) -> new hv; wave 0
//   publishes hv to parity-buffered h1s.
//   Wave 2 (L2): ALL layer-2 work, one step behind — reads h1s[par^1] (=h(t-1),
//   written post-barrier(t-1), read post-barrier(t): one barrier between ->
//   race-free), 4 DPP wave-sum dots + lane-63 scalar recurrence + y store.
// Round-7 post-mortem: step = 1730cyc vs ~480 issue; critical path was
// matvec + act chain + dpp sums (60) + barrier (150) + gls read (120) +
// cell tanh (50) + LAYER-2 TAIL (130, wave 0 only -> barrier skew). Moving
// dpp sums + L2 tail off the compute waves cuts ~190cyc/step and makes the
// compute waves symmetric at the barrier.

#define TT 1024

__device__ __forceinline__ float fsig(float x) {
    return __builtin_amdgcn_rcpf(1.f + __expf(-x));
}
__device__ __forceinline__ float ftanh(float x) {
    return 1.f - 2.f * __builtin_amdgcn_rcpf(1.f + __expf(2.f * x));
}

template <int Ctrl, int Rmask>
__device__ __forceinline__ float dpp_add(float x) {
    int t = __builtin_amdgcn_update_dpp(0, __float_as_int(x), Ctrl, Rmask, 0xf, true);
    return x + __int_as_float(t);
}
// Sum across 64 lanes; result valid in lane 63. 6 dependent VALU pairs.
__device__ __forceinline__ float wave_sum64(float x) {
    x = dpp_add<0x111, 0xf>(x); // row_shr:1
    x = dpp_add<0x112, 0xf>(x); // row_shr:2
    x = dpp_add<0x114, 0xf>(x); // row_shr:4
    x = dpp_add<0x118, 0xf>(x); // row_shr:8
    x = dpp_add<0x142, 0xa>(x); // row_bcast:15
    x = dpp_add<0x143, 0xc>(x); // row_bcast:31 ; lane63 = total
    return x;
}

// Broadcast lane `l` of v to all lanes via SGPR (no LDS, exec-independent).
__device__ __forceinline__ float bcast(float v, int l) {
    return __uint_as_float(__builtin_amdgcn_readlane(__float_as_uint(v), l));
}

__global__ __attribute__((amdgpu_waves_per_eu(1, 1))) __launch_bounds__(192)
void lstm2_kernel(
    const float* __restrict__ x,    // [B, T]
    const float* __restrict__ W1,   // [65, 256]; row0 = x, rows 1..64 = h1
    const float* __restrict__ b1,   // [256]
    const float* __restrict__ W2,   // [65, 4]; rows 0..63 = h1, row 64 = h2
    const float* __restrict__ b2,   // [4]
    float* __restrict__ y)          // [B, T]
{
    __shared__ __align__(16) float xs[TT];
    __shared__ __align__(16) float gls[2][4][64];  // [parity][gate][unit] acts
    __shared__ __align__(16) float h1s[2][64];     // [parity][unit] h1 for L2 wave

    const int tid  = threadIdx.x;
    const int lane = tid & 63;
    const int wid  = tid >> 6;       // 0,1 compute; 2 = layer-2
    const int b    = blockIdx.x;

    // stage x row (threads 0..127 x 2 float4 = 4 KB, coalesced)
    if (tid < 128) {
        const float4* src = (const float4*)(x + (size_t)b * TT);
        float4* dst = (float4*)xs;
        dst[tid]       = src[tid];
        dst[128 + tid] = src[128 + tid];
    }

    float* yrow = y + (size_t)b * TT;

    if (wid < 2) {
        // ---------------- compute waves ----------------
        const int ga = wid << 1, gb = ga | 1;       // this wave's two gates
        const int ca = (ga << 6) | lane;            // gate columns for unit lane
        const int cb = (gb << 6) | lane;

        // weights: 2 full columns in VGPRs
        float wxa = W1[ca], wxb = W1[cb];
        float bsa = b1[ca], bsb = b1[cb];
        float wha[64], whb[64];
#pragma unroll
        for (int j = 0; j < 64; ++j) {
            wha[j] = W1[(j + 1) * 256 + ca];
            whb[j] = W1[(j + 1) * 256 + cb];
        }
        // one-shot opacity: loop-used weights become asm results -> non-rematable
#define PIN4(A, B, C, D) asm volatile("" : "+v"(A), "+v"(B), "+v"(C), "+v"(D))
#pragma unroll
        for (int j = 0; j < 64; j += 4) {
            PIN4(wha[j], wha[j + 1], wha[j + 2], wha[j + 3]);
            PIN4(whb[j], whb[j + 1], whb[j + 2], whb[j + 3]);
        }
        PIN4(wxa, wxb, bsa, bsb);
#undef PIN4

        // unified activation constants (wave-uniform):
        const float L2E = 1.4426950408889634f;
        const float mma = -L2E;
        const float kka = (ga == 2) ? -L2E : 0.f;
        const float mmb = (gb == 1) ? 2.f * L2E : -L2E;
        const float aab = (gb == 1) ? 1.f : 0.f;
        const float bbb = (gb == 1) ? -2.f : 1.f;

        float c1 = 0.f, hv = 0.f;     // layer-1 state of unit lane (per-wave copy)
        __syncthreads();              // xs staged

        // One step; PAR compile-time. Matvec j-outer: each broadcast quad
        // feeds both gates (8 FMA / 4 readlane). Summation: 4-way split
        // accumulators, (a0+a1)+(a2+a3) — rounds 3-7 numerics.
#define STEP(PAR, XT) { \
        float a0 = fmaf((XT), wxa, bsa), a1 = 0.f, a2 = 0.f, a3 = 0.f; \
        float e0 = fmaf((XT), wxb, bsb), e1 = 0.f, e2 = 0.f, e3 = 0.f; \
        _Pragma("unroll") \
        for (int j = 0; j < 64; j += 4) { \
            const float s0 = bcast(hv, j + 0), s1 = bcast(hv, j + 1); \
            const float s2 = bcast(hv, j + 2), s3 = bcast(hv, j + 3); \
            a0 = fmaf(s0, wha[j + 0], a0); e0 = fmaf(s0, whb[j + 0], e0); \
            a1 = fmaf(s1, wha[j + 1], a1); e1 = fmaf(s1, whb[j + 1], e1); \
            a2 = fmaf(s2, wha[j + 2], a2); e2 = fmaf(s2, whb[j + 2], e2); \
            a3 = fmaf(s3, wha[j + 3], a3); e3 = fmaf(s3, whb[j + 3], e3); \
        } \
        const float pa = (a0 + a1) + (a2 + a3); \
        const float pb = (e0 + e1) + (e2 + e3); \
        const float acta = __builtin_amdgcn_rcpf(1.f + exp2f(fmaf(mma, pa, kka))); \
        const float actb = fmaf(bbb, __builtin_amdgcn_rcpf(1.f + exp2f(mmb * pb)), aab); \
        gls[PAR][ga][lane] = acta; \
        gls[PAR][gb][lane] = actb; \
        __syncthreads();          /* the ONLY barrier per step */ \
        { \
            const float i_ = gls[PAR][0][lane], j_ = gls[PAR][1][lane]; \
            const float f_ = gls[PAR][2][lane], o_ = gls[PAR][3][lane]; \
            c1 = fmaf(c1, f_, i_ * j_); \
            hv = ftanh(c1) * o_; \
            if (wid == 0) h1s[PAR][lane] = hv;   /* publish h(t) for L2 wave */ \
        } }

        for (int t = 0; t < TT; t += 4) {
            const float4 x4 = *(const float4*)(xs + t);
            STEP(0, x4.x)
            STEP(1, x4.y)
            STEP(0, x4.z)
            STEP(1, x4.w)
        }
#undef STEP
        __syncthreads();              // tail barrier (publish h1(TT-1))
    } else {
        // ---------------- wave 2: full layer 2, one step behind ----------------
        const float4 w2g4 = *(const float4*)(W2 + lane * 4);   // W2[lane][0..3]
        const float w2h0 = W2[256], w2h1 = W2[257], w2h2 = W2[258], w2h3 = W2[259];
        const float b20 = b2[0], b21 = b2[1], b22 = b2[2], b23 = b2[3];
        float c2 = 0.f, h2 = 0.f;     // state lives in lane 63
        __syncthreads();              // matches compute barrier #1

        for (int t = 0; t < TT; ++t) {
            __syncthreads();          // rendezvous with compute mid-step barrier
            if (t > 0) {
                // h(t-1): written post-barrier(t-1), read post-barrier(t) ->
                // one full barrier between write and read: race-free.
                const float hv = h1s[(t - 1) & 1][lane];
                const float d0 = wave_sum64(hv * w2g4.x);
                const float d1 = wave_sum64(hv * w2g4.y);
                const float d2 = wave_sum64(hv * w2g4.z);
                const float d3 = wave_sum64(hv * w2g4.w);
                if (lane == 63) {
                    const float i2 = fsig (fmaf(h2, w2h0, d0) + b20);
                    const float j2 = ftanh(fmaf(h2, w2h1, d1) + b21);
                    const float f2 = fsig (fmaf(h2, w2h2, d2) + b22 + 1.f);
                    const float o2 = fsig (fmaf(h2, w2h3, d3) + b23);
                    c2 = fmaf(c2, f2, i2 * j2);
                    h2 = ftanh(c2) * o2;
                    yrow[t - 1] = h2;
                }
            }
        }
        __syncthreads();              // matches compute tail barrier
        {   // final step: y[TT-1] from h1(TT-1)
            const float hv = h1s[(TT - 1) & 1][lane];
            const float d0 = wave_sum64(hv * w2g4.x);
            const float d1 = wave_sum64(hv * w2g4.y);
            const float d2 = wave_sum64(hv * w2g4.z);
            const float d3 = wave_sum64(hv * w2g4.w);
            if (lane == 63) {
                const float i2 = fsig (fmaf(h2, w2h0, d0) + b20);
                const float j2 = ftanh(fmaf(h2, w2h1, d1) + b21);
                const float f2 = fsig (fmaf(h2, w2h2, d2) + b22 + 1.f);
                const float o2 = fsig (fmaf(h2, w2h3, d3) + b23);
                c2 = fmaf(c2, f2, i2 * j2);
                h2 = ftanh(c2) * o2;
                yrow[TT - 1] = h2;
            }
        }
    }
}

extern "C" void kernel_launch(void* const* d_in, const int* in_sizes, int n_in,
                              void* d_out, int out_size, void* d_ws, size_t ws_size,
                              hipStream_t stream) {
    const float* x  = (const float*)d_in[0];
    const float* W1 = (const float*)d_in[1];
    const float* b1 = (const float*)d_in[2];
    const float* W2 = (const float*)d_in[3];
    const float* b2 = (const float*)d_in[4];
    float* y = (float*)d_out;
    lstm2_kernel<<<512, 192, 0, stream>>>(x, W1, b1, W2, b2, y);
}

// Round 9
// 979.636 us; speedup vs baseline: 1.1532x; 1.1532x over previous
//
#include <hip/hip_runtime.h>

// 2-layer LSTM, B=512, T=1024, H=64 (tf LSTMCell, gates i,j,f,o, forget bias 1.0)
//
// ROUND-9: round-8 structure, occupancy fix.
//   Round 8 (waves_per_eu(1,1)) capped residency at 4 waves/CU, so the
//   3-wave blocks ran ONE per CU -> 512 blocks in 2 sequential passes
//   (occupancy 9.1%, dur 1130us; per-pass step = ~1295cyc, 435cyc better
//   than round 7's in-wave-L2 structure). Fix: amdgpu_waves_per_eu(1,2) —
//   min=1 keeps the 512-VGPR budget (weight residency preserved: VGPR=132,
//   no remat/spill), max=2 lifts the runtime cap to 8 waves/CU so both
//   3-wave blocks co-reside (6 waves/CU).
//
// Structure: 3 waves per batch element (192 thr), grid 512 (2 blocks/CU).
//   Waves 0-1 (compute): wave w owns gates {2w, 2w+1} = 130 W1 weights in
//   VGPRs (resident via one-shot opaque asm pins). Per step: 64 readlane
//   broadcasts of register-resident hv feed 128 FMAs; acts -> gls (gate-major,
//   conflict-free); ONE barrier; cell update (replicated) -> new hv; wave 0
//   publishes hv to parity-buffered h1s.
//   Wave 2 (L2): ALL layer-2 work, one step behind — reads h1s[par^1]
//   (write->barrier->read: race-free), 4 DPP wave-sum dots + lane-63 scalar
//   recurrence + y store.

#define TT 1024

__device__ __forceinline__ float fsig(float x) {
    return __builtin_amdgcn_rcpf(1.f + __expf(-x));
}
__device__ __forceinline__ float ftanh(float x) {
    return 1.f - 2.f * __builtin_amdgcn_rcpf(1.f + __expf(2.f * x));
}

template <int Ctrl, int Rmask>
__device__ __forceinline__ float dpp_add(float x) {
    int t = __builtin_amdgcn_update_dpp(0, __float_as_int(x), Ctrl, Rmask, 0xf, true);
    return x + __int_as_float(t);
}
// Sum across 64 lanes; result valid in lane 63. 6 dependent VALU pairs.
__device__ __forceinline__ float wave_sum64(float x) {
    x = dpp_add<0x111, 0xf>(x); // row_shr:1
    x = dpp_add<0x112, 0xf>(x); // row_shr:2
    x = dpp_add<0x114, 0xf>(x); // row_shr:4
    x = dpp_add<0x118, 0xf>(x); // row_shr:8
    x = dpp_add<0x142, 0xa>(x); // row_bcast:15
    x = dpp_add<0x143, 0xc>(x); // row_bcast:31 ; lane63 = total
    return x;
}

// Broadcast lane `l` of v to all lanes via SGPR (no LDS, exec-independent).
__device__ __forceinline__ float bcast(float v, int l) {
    return __uint_as_float(__builtin_amdgcn_readlane(__float_as_uint(v), l));
}

__global__ __attribute__((amdgpu_waves_per_eu(1, 2))) __launch_bounds__(192)
void lstm2_kernel(
    const float* __restrict__ x,    // [B, T]
    const float* __restrict__ W1,   // [65, 256]; row0 = x, rows 1..64 = h1
    const float* __restrict__ b1,   // [256]
    const float* __restrict__ W2,   // [65, 4]; rows 0..63 = h1, row 64 = h2
    const float* __restrict__ b2,   // [4]
    float* __restrict__ y)          // [B, T]
{
    __shared__ __align__(16) float xs[TT];
    __shared__ __align__(16) float gls[2][4][64];  // [parity][gate][unit] acts
    __shared__ __align__(16) float h1s[2][64];     // [parity][unit] h1 for L2 wave

    const int tid  = threadIdx.x;
    const int lane = tid & 63;
    const int wid  = tid >> 6;       // 0,1 compute; 2 = layer-2
    const int b    = blockIdx.x;

    // stage x row (threads 0..127 x 2 float4 = 4 KB, coalesced)
    if (tid < 128) {
        const float4* src = (const float4*)(x + (size_t)b * TT);
        float4* dst = (float4*)xs;
        dst[tid]       = src[tid];
        dst[128 + tid] = src[128 + tid];
    }

    float* yrow = y + (size_t)b * TT;

    if (wid < 2) {
        // ---------------- compute waves ----------------
        const int ga = wid << 1, gb = ga | 1;       // this wave's two gates
        const int ca = (ga << 6) | lane;            // gate columns for unit lane
        const int cb = (gb << 6) | lane;

        // weights: 2 full columns in VGPRs
        float wxa = W1[ca], wxb = W1[cb];
        float bsa = b1[ca], bsb = b1[cb];
        float wha[64], whb[64];
#pragma unroll
        for (int j = 0; j < 64; ++j) {
            wha[j] = W1[(j + 1) * 256 + ca];
            whb[j] = W1[(j + 1) * 256 + cb];
        }
        // one-shot opacity: loop-used weights become asm results -> non-rematable
#define PIN4(A, B, C, D) asm volatile("" : "+v"(A), "+v"(B), "+v"(C), "+v"(D))
#pragma unroll
        for (int j = 0; j < 64; j += 4) {
            PIN4(wha[j], wha[j + 1], wha[j + 2], wha[j + 3]);
            PIN4(whb[j], whb[j + 1], whb[j + 2], whb[j + 3]);
        }
        PIN4(wxa, wxb, bsa, bsb);
#undef PIN4

        // unified activation constants (wave-uniform):
        const float L2E = 1.4426950408889634f;
        const float mma = -L2E;
        const float kka = (ga == 2) ? -L2E : 0.f;
        const float mmb = (gb == 1) ? 2.f * L2E : -L2E;
        const float aab = (gb == 1) ? 1.f : 0.f;
        const float bbb = (gb == 1) ? -2.f : 1.f;

        float c1 = 0.f, hv = 0.f;     // layer-1 state of unit lane (per-wave copy)
        __syncthreads();              // xs staged

        // One step; PAR compile-time. Matvec j-outer: each broadcast quad
        // feeds both gates (8 FMA / 4 readlane). Summation: 4-way split
        // accumulators, (a0+a1)+(a2+a3) — rounds 3-8 numerics.
#define STEP(PAR, XT) { \
        float a0 = fmaf((XT), wxa, bsa), a1 = 0.f, a2 = 0.f, a3 = 0.f; \
        float e0 = fmaf((XT), wxb, bsb), e1 = 0.f, e2 = 0.f, e3 = 0.f; \
        _Pragma("unroll") \
        for (int j = 0; j < 64; j += 4) { \
            const float s0 = bcast(hv, j + 0), s1 = bcast(hv, j + 1); \
            const float s2 = bcast(hv, j + 2), s3 = bcast(hv, j + 3); \
            a0 = fmaf(s0, wha[j + 0], a0); e0 = fmaf(s0, whb[j + 0], e0); \
            a1 = fmaf(s1, wha[j + 1], a1); e1 = fmaf(s1, whb[j + 1], e1); \
            a2 = fmaf(s2, wha[j + 2], a2); e2 = fmaf(s2, whb[j + 2], e2); \
            a3 = fmaf(s3, wha[j + 3], a3); e3 = fmaf(s3, whb[j + 3], e3); \
        } \
        const float pa = (a0 + a1) + (a2 + a3); \
        const float pb = (e0 + e1) + (e2 + e3); \
        const float acta = __builtin_amdgcn_rcpf(1.f + exp2f(fmaf(mma, pa, kka))); \
        const float actb = fmaf(bbb, __builtin_amdgcn_rcpf(1.f + exp2f(mmb * pb)), aab); \
        gls[PAR][ga][lane] = acta; \
        gls[PAR][gb][lane] = actb; \
        __syncthreads();          /* the ONLY barrier per step */ \
        { \
            const float i_ = gls[PAR][0][lane], j_ = gls[PAR][1][lane]; \
            const float f_ = gls[PAR][2][lane], o_ = gls[PAR][3][lane]; \
            c1 = fmaf(c1, f_, i_ * j_); \
            hv = ftanh(c1) * o_; \
            if (wid == 0) h1s[PAR][lane] = hv;   /* publish h(t) for L2 wave */ \
        } }

        for (int t = 0; t < TT; t += 4) {
            const float4 x4 = *(const float4*)(xs + t);
            STEP(0, x4.x)
            STEP(1, x4.y)
            STEP(0, x4.z)
            STEP(1, x4.w)
        }
#undef STEP
        __syncthreads();              // tail barrier (publish h1(TT-1))
    } else {
        // ---------------- wave 2: full layer 2, one step behind ----------------
        const float4 w2g4 = *(const float4*)(W2 + lane * 4);   // W2[lane][0..3]
        const float w2h0 = W2[256], w2h1 = W2[257], w2h2 = W2[258], w2h3 = W2[259];
        const float b20 = b2[0], b21 = b2[1], b22 = b2[2], b23 = b2[3];
        float c2 = 0.f, h2 = 0.f;     // state lives in lane 63
        __syncthreads();              // matches compute barrier #1

        for (int t = 0; t < TT; ++t) {
            __syncthreads();          // rendezvous with compute mid-step barrier
            if (t > 0) {
                // h(t-1): written post-barrier(t-1), read post-barrier(t) ->
                // one full barrier between write and read: race-free.
                const float hv = h1s[(t - 1) & 1][lane];
                const float d0 = wave_sum64(hv * w2g4.x);
                const float d1 = wave_sum64(hv * w2g4.y);
                const float d2 = wave_sum64(hv * w2g4.z);
                const float d3 = wave_sum64(hv * w2g4.w);
                if (lane == 63) {
                    const float i2 = fsig (fmaf(h2, w2h0, d0) + b20);
                    const float j2 = ftanh(fmaf(h2, w2h1, d1) + b21);
                    const float f2 = fsig (fmaf(h2, w2h2, d2) + b22 + 1.f);
                    const float o2 = fsig (fmaf(h2, w2h3, d3) + b23);
                    c2 = fmaf(c2, f2, i2 * j2);
                    h2 = ftanh(c2) * o2;
                    yrow[t - 1] = h2;
                }
            }
        }
        __syncthreads();              // matches compute tail barrier
        {   // final step: y[TT-1] from h1(TT-1)
            const float hv = h1s[(TT - 1) & 1][lane];
            const float d0 = wave_sum64(hv * w2g4.x);
            const float d1 = wave_sum64(hv * w2g4.y);
            const float d2 = wave_sum64(hv * w2g4.z);
            const float d3 = wave_sum64(hv * w2g4.w);
            if (lane == 63) {
                const float i2 = fsig (fmaf(h2, w2h0, d0) + b20);
                const float j2 = ftanh(fmaf(h2, w2h1, d1) + b21);
                const float f2 = fsig (fmaf(h2, w2h2, d2) + b22 + 1.f);
                const float o2 = fsig (fmaf(h2, w2h3, d3) + b23);
                c2 = fmaf(c2, f2, i2 * j2);
                h2 = ftanh(c2) * o2;
                yrow[TT - 1] = h2;
            }
        }
    }
}

extern "C" void kernel_launch(void* const* d_in, const int* in_sizes, int n_in,
                              void* d_out, int out_size, void* d_ws, size_t ws_size,
                              hipStream_t stream) {
    const float* x  = (const float*)d_in[0];
    const float* W1 = (const float*)d_in[1];
    const float* b1 = (const float*)d_in[2];
    const float* W2 = (const float*)d_in[3];
    const float* b2 = (const float*)d_in[4];
    float* y = (float*)d_out;
    lstm2_kernel<<<512, 192, 0, stream>>>(x, W1, b1, W2, b2, y);
}